// Round 5
// baseline (255.868 us; speedup 1.0000x reference)
//
#include <hip/hip_runtime.h>
#include <math.h>

// Problem constants (B=2, S=2048, D=1024, H=16, hd=64, K=16)
#define SEQ 2048
#define DIM 1024
#define NB  2
#define NH  16

typedef __attribute__((ext_vector_type(8))) short short8;
typedef __attribute__((ext_vector_type(4))) float floatx4;
typedef __attribute__((ext_vector_type(16))) float floatx16;

__device__ __forceinline__ ushort f2bf(float f) {
    unsigned u = __float_as_uint(f);
    return (ushort)((u + 0x7FFFu + ((u >> 16) & 1u)) >> 16);
}
__device__ __forceinline__ float bf2f(ushort h) {
    return __uint_as_float(((unsigned)h) << 16);
}
// async global->LDS, 16B per lane; LDS dest = wave-uniform base + lane*16
__device__ __forceinline__ void gload16(const void* g, char* lds_base) {
    __builtin_amdgcn_global_load_lds(
        (const __attribute__((address_space(1))) void*)g,
        (__attribute__((address_space(3))) void*)lds_base, 16, 0, 0);
}
// packed f32x2 -> bf16x2 (RNE), low word = a
__device__ __forceinline__ unsigned cvtpk(float a, float b) {
    unsigned r;
    asm("v_cvt_pk_bf16_f32 %0, %1, %2" : "=v"(r) : "v"(a), "v"(b));
    return r;
}
// swap: a -> [a.lo32 | b.lo32], b -> [a.hi32 | b.hi32]
__device__ __forceinline__ void plswap(unsigned &a, unsigned &b) {
    asm("v_permlane32_swap_b32 %0, %1" : "+v"(a), "+v"(b));
}

// ---------------------------------------------------------------------------
// Dispatch A: everything that depends only on kernel inputs.
//  blocks [0,4096):    x fp32 -> xh + xl (split)
//  blocks [4096,6144): qkv_w q/k rows -> wh (hi only)
//  blocks [6144,7168): qkv_w v rows   -> wh+2M (hi) + wlv (lo)
//  blocks [7168,8192): traj stats (4 diff-rows per block)
//  blocks [8192,9216): out_w -> owh + owl (split)
// ---------------------------------------------------------------------------
__global__ __launch_bounds__(256) void front_kernel(
    const float* __restrict__ x, const float* __restrict__ qkv_w,
    const float* __restrict__ out_w,
    ushort* __restrict__ xh, ushort* __restrict__ xl,
    ushort* __restrict__ wh, ushort* __restrict__ wlv,
    ushort* __restrict__ owh, ushort* __restrict__ owl,
    float* __restrict__ sbuf, float* __restrict__ invbuf)
{
    const int blk = blockIdx.x;
    if (blk < 4096) {
        int i = blk * 1024 + threadIdx.x * 4;
        float4 v = *(const float4*)(x + i);
        ushort4 h, l;
        h.x = f2bf(v.x); l.x = f2bf(v.x - bf2f(h.x));
        h.y = f2bf(v.y); l.y = f2bf(v.y - bf2f(h.y));
        h.z = f2bf(v.z); l.z = f2bf(v.z - bf2f(h.z));
        h.w = f2bf(v.w); l.w = f2bf(v.w - bf2f(h.w));
        *(ushort4*)(xh + i) = h;
        *(ushort4*)(xl + i) = l;
    } else if (blk < 6144) {
        int i = (blk - 4096) * 1024 + threadIdx.x * 4;
        float4 v = *(const float4*)(qkv_w + i);
        ushort4 o;
        o.x = f2bf(v.x); o.y = f2bf(v.y); o.z = f2bf(v.z); o.w = f2bf(v.w);
        *(ushort4*)(wh + i) = o;
    } else if (blk < 7168) {
        int i = (blk - 6144) * 1024 + threadIdx.x * 4;
        float4 v = *(const float4*)(qkv_w + 2097152 + i);
        ushort4 h, l;
        h.x = f2bf(v.x); l.x = f2bf(v.x - bf2f(h.x));
        h.y = f2bf(v.y); l.y = f2bf(v.y - bf2f(h.y));
        h.z = f2bf(v.z); l.z = f2bf(v.z - bf2f(h.z));
        h.w = f2bf(v.w); l.w = f2bf(v.w - bf2f(h.w));
        *(ushort4*)(wh + 2097152 + i) = h;
        *(ushort4*)(wlv + i) = l;
    } else if (blk < 8192) {
        const int wave = threadIdx.x >> 6;
        const int lane = threadIdx.x & 63;
        const int row  = (blk - 7168) * 4 + wave;
        const int NR = NB * (SEQ - 1);
        if (row >= NR) return;
        const int b = row / (SEQ - 1);
        const int j = row - b * (SEQ - 1);
        const float* x0 = x + ((size_t)(b * SEQ + j)) * DIM;
        const float* x1 = x0 + DIM;
        float sum = 0.f;
        #pragma unroll
        for (int q = 0; q < 4; ++q) {
            int idx = q * 256 + lane * 4;
            float4 a = *(const float4*)(x0 + idx);
            float4 c = *(const float4*)(x1 + idx);
            float dx = c.x-a.x, dy = c.y-a.y, dz = c.z-a.z, dw = c.w-a.w;
            sum += dx*dx + dy*dy + dz*dz + dw*dw;
        }
        #pragma unroll
        for (int off = 32; off > 0; off >>= 1) sum += __shfl_down(sum, off);
        if (lane == 0) {
            float mag = sqrtf(sum);
            sbuf[row]   = tanhf(mag);
            invbuf[row] = 1.0f / fmaxf(mag, 1e-8f);
        }
    } else {
        int i = (blk - 8192) * 1024 + threadIdx.x * 4;
        float4 v = *(const float4*)(out_w + i);
        ushort4 h, l;
        h.x = f2bf(v.x); l.x = f2bf(v.x - bf2f(h.x));
        h.y = f2bf(v.y); l.y = f2bf(v.y - bf2f(h.y));
        h.z = f2bf(v.z); l.z = f2bf(v.z - bf2f(h.z));
        h.w = f2bf(v.w); l.w = f2bf(v.w - bf2f(h.w));
        *(ushort4*)(owh + i) = h;
        *(ushort4*)(owl + i) = l;
    }
}

// ---------------------------------------------------------------------------
// traj combine body (window <= 8), one block per (b, pos)
// ---------------------------------------------------------------------------
__device__ __forceinline__ void traj_body(
    int bp, const float* __restrict__ x, const float* __restrict__ sbuf,
    const float* __restrict__ invbuf, float* __restrict__ traj_out)
{
    const int b  = bp >> 11;
    const int p  = bp & (SEQ - 1);
    int ws = p - 8; if (ws < 0) ws = 0;
    const int wlen = p - ws;
    const float wsz = (float)((p - ws) > 1 ? (p - ws) : 1);
    const int base = b * (SEQ - 1) + ws;

    float Z = 0.f;
    for (int t = 0; t < wlen; ++t)
        Z += sbuf[base + t] * ((float)(t + 1) / wsz);
    const float scale = 1.0f / fmaxf(Z, 1e-8f);

    const int d0 = threadIdx.x * 4;
    const float* xb = x + ((size_t)(b * SEQ + ws)) * DIM + d0;
    float4 prev = *(const float4*)xb;
    float4 acc = make_float4(0.f,0.f,0.f,0.f);
    for (int t = 0; t < wlen; ++t) {
        xb += DIM;
        float4 cur = *(const float4*)xb;
        float cc = sbuf[base + t] * ((float)(t + 1) / wsz) * invbuf[base + t] * scale;
        acc.x += cc * (cur.x - prev.x);
        acc.y += cc * (cur.y - prev.y);
        acc.z += cc * (cur.z - prev.z);
        acc.w += cc * (cur.w - prev.w);
        prev = cur;
    }
    *(float4*)(traj_out + (size_t)bp * DIM + d0) = acc;
}

// ---------------------------------------------------------------------------
// MFMA bf16 GEMM body: C[M,N] = A[M,1024] @ B[N,1024]^T.  Tile 128 x BN,
// BK=32, 4 waves 2x2 (wave tile 64 x BN/2), 16x16x32 MFMAs.
// SPLIT=1: A ~= Ah+Al, B ~= Bh+Bl; C = Ah·Bh + Ah·Bl + Al·Bh (fp32-ish).
// EPI=0: fp32 store to cout (ldc).
// EPI=2 (v^T): bf16 store to qwb[b][m][token&2047]  (vbt layout [B,1024,S]).
// ---------------------------------------------------------------------------
template<int SPLIT, int EPI, int BN>
__device__ __forceinline__ void gemm_body(
    int bx, int by, char* smem,
    const ushort* __restrict__ Ah, const ushort* __restrict__ Al,
    const ushort* __restrict__ Bh, const ushort* __restrict__ Bl,
    float* __restrict__ cout, int ldc,
    ushort* __restrict__ qwb)
{
    constexpr int JT   = BN / 32;                    // N frags per wave
    constexpr int BSZ  = BN * 64;                    // B tile bytes (BN rows x 64B)
    constexpr int HALF = 8192 + BSZ;                 // one precision level (A+B)
    const int tid = threadIdx.x;
    const int l = tid & 63;
    const int w = tid >> 6;
    const int wm = w >> 1, wn = w & 1;
    const int n0 = bx * BN;
    const int m0 = by * 128;

    char* a_h = smem;
    char* b_h = smem + 8192;
    char* a_l = smem + HALF;
    char* b_l = smem + HALF + 8192;

    const int srowA = 32 * w + (l >> 2);
    const int srowB = (BN == 128 ? 32 * w : 16 * w) + (l >> 2);
    const int scol  = (l & 3) * 8;
    const ushort* Ahg = Ah + (size_t)(m0 + srowA) * 1024 + scol;
    const ushort* Bhg = Bh + (size_t)(n0 + srowB) * 1024 + scol;
    const ushort* Alg = SPLIT ? Al + (size_t)(m0 + srowA) * 1024 + scol : nullptr;
    const ushort* Blg = SPLIT ? Bl + (size_t)(n0 + srowB) * 1024 + scol : nullptr;

    floatx4 acc[4][JT] = {};
    const int fr = l & 15;
    const int fq = (l >> 4) * 16;

    for (int kb = 0; kb < 1024; kb += 32) {
        if (kb) __syncthreads();
        gload16(Ahg + kb,             a_h + w*2048);
        gload16(Ahg + kb + 16*1024,   a_h + w*2048 + 1024);
        if (BN == 128) {
            gload16(Bhg + kb,             b_h + w*2048);
            gload16(Bhg + kb + 16*1024,   b_h + w*2048 + 1024);
        } else {
            gload16(Bhg + kb,             b_h + w*1024);
        }
        if (SPLIT) {
            gload16(Alg + kb,           a_l + w*2048);
            gload16(Alg + kb + 16*1024, a_l + w*2048 + 1024);
            if (BN == 128) {
                gload16(Blg + kb,           b_l + w*2048);
                gload16(Blg + kb + 16*1024, b_l + w*2048 + 1024);
            } else {
                gload16(Blg + kb,           b_l + w*1024);
            }
        }
        __syncthreads();
        short8 fah[4], fbh[JT], fal[4], fbl[JT];
        #pragma unroll
        for (int t = 0; t < 4; ++t) {
            fah[t] = *(const short8*)(a_h + ((wm*64 + t*16 + fr) << 6) + fq);
            if (SPLIT)
                fal[t] = *(const short8*)(a_l + ((wm*64 + t*16 + fr) << 6) + fq);
        }
        #pragma unroll
        for (int t = 0; t < JT; ++t) {
            fbh[t] = *(const short8*)(b_h + ((wn*(BN/2) + t*16 + fr) << 6) + fq);
            if (SPLIT)
                fbl[t] = *(const short8*)(b_l + ((wn*(BN/2) + t*16 + fr) << 6) + fq);
        }
        #pragma unroll
        for (int it = 0; it < 4; ++it)
            #pragma unroll
            for (int jt = 0; jt < JT; ++jt) {
                acc[it][jt] = __builtin_amdgcn_mfma_f32_16x16x32_bf16(
                    fah[it], fbh[jt], acc[it][jt], 0, 0, 0);
                if (SPLIT) {
                    acc[it][jt] = __builtin_amdgcn_mfma_f32_16x16x32_bf16(
                        fah[it], fbl[jt], acc[it][jt], 0, 0, 0);
                    acc[it][jt] = __builtin_amdgcn_mfma_f32_16x16x32_bf16(
                        fal[it], fbh[jt], acc[it][jt], 0, 0, 0);
                }
            }
    }

    const int row0 = (l >> 4) * 4;   // C: row=(l>>4)*4+reg, col=l&15
    const int col  = l & 15;

    if (EPI == 0) {
        #pragma unroll
        for (int it = 0; it < 4; ++it)
            #pragma unroll
            for (int jt = 0; jt < JT; ++jt)
                #pragma unroll
                for (int r = 0; r < 4; ++r) {
                    int gm = m0 + wm*64 + it*16 + row0 + r;
                    int gn = n0 + wn*(BN/2) + jt*16 + col;
                    cout[(size_t)gm * ldc + gn] = acc[it][jt][r];
                }
    } else {
        // transposed v store: rows m = h*64+d, cols n = token
        #pragma unroll
        for (int it = 0; it < 4; ++it)
            #pragma unroll
            for (int jt = 0; jt < JT; ++jt)
                #pragma unroll
                for (int r = 0; r < 4; ++r) {
                    int md = m0 + wm*64 + it*16 + row0 + r;
                    int t  = n0 + wn*(BN/2) + jt*16 + col;
                    int bb = t >> 11, ss = t & (SEQ - 1);
                    qwb[((size_t)bb << 21) + (size_t)md * SEQ + ss] = f2bf(acc[it][jt][r]);
                }
    }
}

// ---------------------------------------------------------------------------
// qk GEMM (plain bf16, BN=128) with FUSED splat epilogue: never materializes
// q/k. Wave tile = 64 tokens x one full head (64 dims). After the K-loop:
//  1) barrier; store wave's 64x64 tile as bf16 to private LDS, XOR-swizzled
//     at 16B granularity (block ^= tok&7) for conflict-free b128 readback;
//  2) lane = token: read its 64 dims (8x ds_read_b128, conflict-free);
//  3) dq_sp = sum_i (q_i - c_sp_i)^2 with centers staged in LDS (block's 2
//     heads = contiguous 8KB of centers[]);
//  4) w_sp = exp(-0.5*dq/s^2)*sigmoid(amp); 32B store to weight buffer.
// ---------------------------------------------------------------------------
__device__ __forceinline__ void qk_splat_body(
    int bx, int by, char* smem,
    const ushort* __restrict__ Ah, const ushort* __restrict__ Bh,
    ushort* __restrict__ qwb, ushort* __restrict__ kwb,
    const float* __restrict__ centers, const float* __restrict__ lscales,
    const float* __restrict__ amps)
{
    const int tid = threadIdx.x;
    const int l = tid & 63;
    const int w = tid >> 6;
    const int wm = w >> 1, wn = w & 1;
    const int n0 = bx * 128;
    const int m0 = by * 128;
    char* a_h = smem;
    char* b_h = smem + 8192;
    float* Cst = (float*)(smem + 32768);   // [2 heads][16 sp][64] f32, 8KB

    // stage this block's two heads of centers (contiguous in centers[])
    {
        const float* src = centers + (size_t)((n0 & 1023) >> 6) * 1024;
        float4 v0 = *(const float4*)(src + tid*8);
        float4 v1 = *(const float4*)(src + tid*8 + 4);
        *(float4*)(Cst + tid*8)     = v0;
        *(float4*)(Cst + tid*8 + 4) = v1;
    }

    const int srow = 32 * w + (l >> 2);
    const int scol = (l & 3) * 8;
    const ushort* Ahg = Ah + (size_t)(m0 + srow) * 1024 + scol;
    const ushort* Bhg = Bh + (size_t)(n0 + srow) * 1024 + scol;

    floatx4 acc[4][4] = {};
    const int fr = l & 15;
    const int fq = (l >> 4) * 16;

    for (int kb = 0; kb < 1024; kb += 32) {
        if (kb) __syncthreads();
        gload16(Ahg + kb,             a_h + w*2048);
        gload16(Ahg + kb + 16*1024,   a_h + w*2048 + 1024);
        gload16(Bhg + kb,             b_h + w*2048);
        gload16(Bhg + kb + 16*1024,   b_h + w*2048 + 1024);
        __syncthreads();
        short8 fah[4], fbh[4];
        #pragma unroll
        for (int t = 0; t < 4; ++t) {
            fah[t] = *(const short8*)(a_h + ((wm*64 + t*16 + fr) << 6) + fq);
            fbh[t] = *(const short8*)(b_h + ((wn*64 + t*16 + fr) << 6) + fq);
        }
        #pragma unroll
        for (int it = 0; it < 4; ++it)
            #pragma unroll
            for (int jt = 0; jt < 4; ++jt)
                acc[it][jt] = __builtin_amdgcn_mfma_f32_16x16x32_bf16(
                    fah[it], fbh[jt], acc[it][jt], 0, 0, 0);
    }

    // ---- fused splat epilogue ----
    __syncthreads();                       // staging buffers dead; reuse for q-tiles
    const int row0 = (l >> 4) * 4;
    const int col  = l & 15;
    ushort* qt = (ushort*)(smem + w*8192); // this wave's 64x64 bf16 tile

    #pragma unroll
    for (int it = 0; it < 4; ++it)
        #pragma unroll
        for (int jt = 0; jt < 4; ++jt)
            #pragma unroll
            for (int r = 0; r < 4; ++r) {
                int tok = it*16 + row0 + r;
                int c   = jt*16 + col;
                qt[tok*64 + ((((c >> 3) ^ (tok & 7)) << 3) | (c & 7))] =
                    f2bf(acc[it][jt][r]);
            }

    // lane l <-> token l of this wave's tile: read back its 64 dims
    float qv[64];
    #pragma unroll
    for (int j = 0; j < 8; ++j) {
        short8 v = *(const short8*)(qt + l*64 + ((j ^ (l & 7)) << 3));
        #pragma unroll
        for (int i = 0; i < 8; ++i) qv[j*8 + i] = bf2f((ushort)v[i]);
    }

    const int hh = ((n0 & 1023) + wn*64) >> 6;     // this wave's head
    const float* cw = Cst + wn*1024;               // head's centers in LDS
    const int tg = m0 + wm*64 + l;                 // global token
    const int bb = tg >> 11, ss = tg & (SEQ - 1);
    ushort* obuf = (n0 < 1024) ? qwb : kwb;

    ushort o16[16];
    #pragma unroll
    for (int sp = 0; sp < 16; ++sp) {
        const float* cp = cw + sp*64;
        float dq = 0.f;
        #pragma unroll
        for (int i = 0; i < 64; ++i) {
            float t = qv[i] - cp[i];
            dq = fmaf(t, t, dq);
        }
        float s2 = __expf(2.f * lscales[hh*16 + sp]);
        float pa = 1.f / (1.f + __expf(-amps[hh*16 + sp]));
        o16[sp] = f2bf(__expf(dq * (-0.5f / s2)) * pa);
    }
    ushort* op = obuf + (((size_t)(bb*NH + hh))*SEQ + ss)*16;
    *(short8*)(op)     = *(short8*)(o16);
    *(short8*)(op + 8) = *(short8*)(o16 + 8);
}

// ---------------------------------------------------------------------------
// Dispatch MID: all work depending only on dispatch A (mutually independent):
//  blocks [0,512):     v^T = Wv @ x^T (split, BN=64), bf16 [B,1024,S]
//  blocks [512,1024):  q/k projection + fused splat weights (BN=128)
//  blocks [1024,5120): traj combine
// ---------------------------------------------------------------------------
__global__ __launch_bounds__(256) void mid_kernel(
    const ushort* __restrict__ xh, const ushort* __restrict__ xl,
    const ushort* __restrict__ wh, const ushort* __restrict__ wlv,
    ushort* __restrict__ vbt, ushort* __restrict__ qwb, ushort* __restrict__ kwb,
    const float* __restrict__ centers, const float* __restrict__ lscales,
    const float* __restrict__ amps,
    const float* __restrict__ x, const float* __restrict__ sbuf,
    const float* __restrict__ invb, float* __restrict__ traj_out)
{
    __shared__ __align__(16) char smem[40960];
    const int blk = blockIdx.x;
    if (blk < 512) {
        gemm_body<1,2,64>(blk & 63, blk >> 6, smem,
                          wh + 2048*1024, wlv, xh, xl, nullptr, 0, vbt);
    } else if (blk < 1024) {
        const int g = blk - 512;
        qk_splat_body(g & 15, g >> 4, smem, xh, wh,
                      qwb, kwb, centers, lscales, amps);
    } else {
        traj_body(blk - 1024, x, sbuf, invb, traj_out);
    }
}

// Dispatch F: out GEMM (split, BN=64, fp32 out)
__global__ __launch_bounds__(256) void gemmO_kernel(
    const ushort* __restrict__ Ah, const ushort* __restrict__ Al,
    const ushort* __restrict__ Bh, const ushort* __restrict__ Bl,
    float* __restrict__ cout)
{
    __shared__ __align__(16) char smem[2 * (8192 + 64*64)];
    gemm_body<1,0,64>(blockIdx.x, blockIdx.y, smem, Ah, Al, Bh, Bl,
                      cout, 1024, nullptr);
}

// ---------------------------------------------------------------------------
// MFMA flash attention, v3: all-register P (no P LDS round-trip).
// 256 threads / 4 waves (qh, kh); QK quadrant via 1x mfma_32x32x16, exp,
// in-register redistribution to PV A-fragment via cvt_pk + permlane32_swap;
// PV via 4x mfma_32x32x16 from xor-swizzled double-buffered V tile.
// One barrier per 64-key tile; kh-partials combined through LDS at the end.
// ---------------------------------------------------------------------------
__global__ __launch_bounds__(256, 4) void attn_kernel(
    const ushort* __restrict__ qw, const ushort* __restrict__ kw,
    const ushort* __restrict__ vbt, ushort* __restrict__ hoh, ushort* __restrict__ hol)
{
    // [0,16K): V^T double buffer (2 x 8KB, [64 d][8 blk of 16B], blk^=(d&7))
    // [16K,16K+512): z combine buffer
    __shared__ __align__(16) char smem[16384 + 512];
    const int tid = threadIdx.x;
    const int l   = tid & 63;
    const int w   = tid >> 6;        // 0..3
    const int qh  = w >> 1;
    const int kh  = w & 1;
    const int l31 = l & 31;
    const int hi  = l >> 5;
    const int bh = blockIdx.y;
    const int b = bh >> 4;
    const int h = bh & 15;
    const int s0 = blockIdx.x * 64;

    // Q fragment (B operand): query s0+qh*32+l31, splat k = hi*8..+8
    short8 qf = *(const short8*)(qw + ((size_t)bh*SEQ + s0 + qh*32 + l31)*16 + hi*8);

    // K fragment source (A operand), direct from global (L2-hot)
    const ushort* kfp = kw + ((size_t)bh*SEQ + kh*32 + l31)*16 + hi*8;
    const ushort* vtb = vbt + ((size_t)(b*1024 + h*64))*SEQ;

    // V stage sources (pre-swizzled global addr -> linear LDS dest)
    const int dA = w*16 + (l >> 3);
    const int dB = dA + 8;
    const ushort* vsA = vtb + (size_t)dA*SEQ + ((l & 7) ^ (dA & 7))*8;
    const ushort* vsB = vtb + (size_t)dB*SEQ + ((l & 7) ^ (dB & 7))*8;

    floatx16 acc0 = {}, acc1 = {};
    floatx16 zero16 = {};
    float zpart = 0.f;

    // prologue: stage tile 0 into buf 0, load kf for tile 0
    gload16(vsA, smem + w*2048);
    gload16(vsB, smem + w*2048 + 1024);
    short8 kf = *(const short8*)kfp;

    for (int jt = 0; jt < 32; ++jt) {
        __syncthreads();   // drains own vmcnt/lgkm: stage(jt) landed, reads of buf^1 done
        char* bufn = smem + ((jt + 1) & 1)*8192;
        if (jt < 31) {
            gload16(vsA + (jt + 1)*64, bufn + w*2048);
            gload16(vsB + (jt + 1)*64, bufn + w*2048 + 1024);
        }
        // QK^T quadrant: C[key][query], key=(r&3)+8*(r>>2)+4*hi (+kh*32), q=l31 (+qh*32)
        floatx16 sc = __builtin_amdgcn_mfma_f32_32x32x16_bf16(kf, qf, zero16, 0, 0, 0);
        if (jt < 31) kf = *(const short8*)(kfp + (jt + 1)*1024);

        float e[16];
        #pragma unroll
        for (int r = 0; r < 16; ++r) e[r] = __expf(sc[r]);
        float zs = 0.f;
        #pragma unroll
        for (int r = 0; r < 16; ++r) zs += e[r];
        zpart += zs;

        // pack to PV A-fragments (lane q=l31, k=8*hi+0..7)
        unsigned p0 = cvtpk(e[0],  e[1]),  p1 = cvtpk(e[2],  e[3]);
        unsigned p2 = cvtpk(e[4],  e[5]),  p3 = cvtpk(e[6],  e[7]);
        unsigned p4 = cvtpk(e[8],  e[9]),  p5 = cvtpk(e[10], e[11]);
        unsigned p6 = cvtpk(e[12], e[13]), p7 = cvtpk(e[14], e[15]);
        plswap(p0, p2); plswap(p1, p3);   // kseg0: keys kh*32 + 0..15
        plswap(p4, p6); plswap(p5, p7);   // kseg1: keys kh*32 + 16..31
        union { unsigned u[4]; short8 s; } ua, ub;
        ua.u[0] = p0; ua.u[1] = p1; ua.u[2] = p2; ua.u[3] = p3;
        ub.u[0] = p4; ub.u[1] = p5; ub.u[2] = p6; ub.u[3] = p7;

        // PV: O[q][d], V as B operand (lane: d col = l31 (+32*dt), 8 tokens)
        const ushort* buf = (const ushort*)(smem + (jt & 1)*8192);
        #pragma unroll
        for (int dt = 0; dt < 2; ++dt) {
            int row = dt*32 + l31;
            const ushort* vr = buf + row*64;
            int bk0 = (kh*4 + hi)     ^ (row & 7);
            int bk1 = (kh*4 + 2 + hi) ^ (row & 7);
            short8 vb0 = *(const short8*)(vr + bk0*8);
            short8 vb1 = *(const short8*)(vr + bk1*8);
            if (dt == 0) {
                acc0 = __builtin_amdgcn_mfma_f32_32x32x16_bf16(ua.s, vb0, acc0, 0, 0, 0);
                acc0 = __builtin_amdgcn_mfma_f32_32x32x16_bf16(ub.s, vb1, acc0, 0, 0, 0);
            } else {
                acc1 = __builtin_amdgcn_mfma_f32_32x32x16_bf16(ua.s, vb0, acc1, 0, 0, 0);
                acc1 = __builtin_amdgcn_mfma_f32_32x32x16_bf16(ub.s, vb1, acc1, 0, 0, 0);
            }
        }
    }

    __syncthreads();   // drain everything before aliasing V buffers

    float* cb = (float*)smem;              // [qh*32+q][64 d] f32 = 16KB
    float* zb = (float*)(smem + 16384);    // [kh][64] f32 = 512B

    // z across hi halves: both halves end with total for their q
    unsigned za = __float_as_uint(zpart), zc = za;
    plswap(za, zc);
    float zq = __uint_as_float(za) + __uint_as_float(zc);
    if (l31 == l) zb[kh*64 + qh*32 + l31] = zq;   // lanes 0..31 only

    if (kh) {
        #pragma unroll
        for (int r = 0; r < 16; ++r) {
            int q = (r & 3) + 8*(r >> 2) + 4*hi;
            cb[(qh*32 + q)*64 + l31]      = acc0[r];
            cb[(qh*32 + q)*64 + 32 + l31] = acc1[r];
        }
    }
    __syncthreads();
    if (!kh) {
        #pragma unroll
        for (int r = 0; r < 16; ++r) {
            int q = (r & 3) + 8*(r >> 2) + 4*hi;
            float zt = zb[qh*32 + q] + zb[64 + qh*32 + q];
            float inv = 1.0f / zt;
            int s = s0 + qh*32 + q;
            size_t base = ((size_t)(b*SEQ + s))*1024 + h*64;
            float v0 = (acc0[r] + cb[(qh*32 + q)*64 + l31])      * inv;
            float v1 = (acc1[r] + cb[(qh*32 + q)*64 + 32 + l31]) * inv;
            ushort h0 = f2bf(v0);
            ushort h1 = f2bf(v1);
            hoh[base + l31]      = h0;
            hol[base + l31]      = f2bf(v0 - bf2f(h0));
            hoh[base + 32 + l31] = h1;
            hol[base + 32 + l31] = f2bf(v1 - bf2f(h1));
        }
    }
}

// ---------------------------------------------------------------------------
extern "C" void kernel_launch(void* const* d_in, const int* in_sizes, int n_in,
                              void* d_out, int out_size, void* d_ws, size_t ws_size,
                              hipStream_t stream)
{
    const float* x       = (const float*)d_in[0];
    const float* qkv_w   = (const float*)d_in[1];
    const float* out_w   = (const float*)d_in[2];
    const float* centers = (const float*)d_in[3];
    const float* lscales = (const float*)d_in[4];
    const float* amps    = (const float*)d_in[5];
    float* out  = (float*)d_out;                      // [B,S,D]
    float* traj = out + (size_t)NB*SEQ*DIM;           // [B,S,D]

    char* wsb = (char*)d_ws;                          // 40.03 MB total
    ushort* xh   = (ushort*)(wsb);                    // [0,8) MB  bf16 x hi
    ushort* xl   = (ushort*)(wsb + (8u<<20));         // [8,16) MB bf16 x lo
    ushort* wh   = (ushort*)(wsb + (16u<<20));        // [16,22) MB qkv_w hi (3072x1024)
    ushort* wlv  = (ushort*)(wsb + (22u<<20));        // [22,24) MB v-weight lo
    ushort* vbt  = (ushort*)(wsb + (24u<<20));        // [24,32) MB v^T bf16 [B,1024,S]
    ushort* owh  = (ushort*)(wsb + (32u<<20));        // [32,34) MB out_w hi
    ushort* owl  = (ushort*)(wsb + (34u<<20));        // [34,36) MB out_w lo
    ushort* qwbh = (ushort*)(wsb + (36u<<20));        // [36,38) MB q splat weights
    ushort* kwbh = (ushort*)(wsb + (38u<<20));        // [38,40) MB k splat weights
    float*  sbuf = (float*)(wsb + (40u<<20));         // 16 KB
    float*  invb = sbuf + 4096;                       // 16 KB
    // aliases (dead by the time they're written):
    ushort* hoh  = xh;                                // attn out hi (xh dead after MID)
    ushort* hol  = xl;                                // attn out lo (xl dead after MID)

    // A: input conversions + traj stats + out_w split
    front_kernel<<<9216, 256, 0, stream>>>(
        x, qkv_w, out_w, xh, xl, wh, wlv, owh, owl, sbuf, invb);
    // MID: v^T GEMM + qk GEMM w/ fused splat + traj combine (all independent)
    mid_kernel<<<5120, 256, 0, stream>>>(
        xh, xl, wh, wlv, vbt, qwbh, kwbh, centers, lscales, amps,
        x, sbuf, invb, traj);
    // attention
    attn_kernel<<<dim3(32, 32), 256, 0, stream>>>(qwbh, kwbh, vbt, hoh, hol);
    // out = ho @ out_w^T (split, fp32 out)
    gemmO_kernel<<<dim3(16, 32), 256, 0, stream>>>(hoh, hol, owh, owl, out);
}

// Round 6
// 233.697 us; speedup vs baseline: 1.0949x; 1.0949x over previous
//
#include <hip/hip_runtime.h>
#include <math.h>

// Problem constants (B=2, S=2048, D=1024, H=16, hd=64, K=16)
#define SEQ 2048
#define DIM 1024
#define NB  2
#define NH  16

typedef __attribute__((ext_vector_type(8))) short short8;
typedef __attribute__((ext_vector_type(4))) float floatx4;
typedef __attribute__((ext_vector_type(16))) float floatx16;

__device__ __forceinline__ ushort f2bf(float f) {
    unsigned u = __float_as_uint(f);
    return (ushort)((u + 0x7FFFu + ((u >> 16) & 1u)) >> 16);
}
__device__ __forceinline__ float bf2f(ushort h) {
    return __uint_as_float(((unsigned)h) << 16);
}
// async global->LDS, 16B per lane; LDS dest = wave-uniform base + lane*16
__device__ __forceinline__ void gload16(const void* g, char* lds_base) {
    __builtin_amdgcn_global_load_lds(
        (const __attribute__((address_space(1))) void*)g,
        (__attribute__((address_space(3))) void*)lds_base, 16, 0, 0);
}
// packed f32x2 -> bf16x2 (RNE), low word = a
__device__ __forceinline__ unsigned cvtpk(float a, float b) {
    unsigned r;
    asm("v_cvt_pk_bf16_f32 %0, %1, %2" : "=v"(r) : "v"(a), "v"(b));
    return r;
}
// swap: a -> [a.lo32 | b.lo32], b -> [a.hi32 | b.hi32]
__device__ __forceinline__ void plswap(unsigned &a, unsigned &b) {
    asm("v_permlane32_swap_b32 %0, %1" : "+v"(a), "+v"(b));
}

// ---------------------------------------------------------------------------
// Dispatch A: everything that depends only on kernel inputs.
//  blocks [0,4096):    x fp32 -> xh + xl (split)
//  blocks [4096,6144): qkv_w q/k rows -> wh (hi only)
//  blocks [6144,7168): qkv_w v rows   -> wh+2M (hi) + wlv (lo)
//  blocks [7168,8192): traj stats (4 diff-rows per block)
//  blocks [8192,9216): out_w -> owh + owl (split)
// ---------------------------------------------------------------------------
__global__ __launch_bounds__(256) void front_kernel(
    const float* __restrict__ x, const float* __restrict__ qkv_w,
    const float* __restrict__ out_w,
    ushort* __restrict__ xh, ushort* __restrict__ xl,
    ushort* __restrict__ wh, ushort* __restrict__ wlv,
    ushort* __restrict__ owh, ushort* __restrict__ owl,
    float* __restrict__ sbuf, float* __restrict__ invbuf)
{
    const int blk = blockIdx.x;
    if (blk < 4096) {
        int i = blk * 1024 + threadIdx.x * 4;
        float4 v = *(const float4*)(x + i);
        ushort4 h, l;
        h.x = f2bf(v.x); l.x = f2bf(v.x - bf2f(h.x));
        h.y = f2bf(v.y); l.y = f2bf(v.y - bf2f(h.y));
        h.z = f2bf(v.z); l.z = f2bf(v.z - bf2f(h.z));
        h.w = f2bf(v.w); l.w = f2bf(v.w - bf2f(h.w));
        *(ushort4*)(xh + i) = h;
        *(ushort4*)(xl + i) = l;
    } else if (blk < 6144) {
        int i = (blk - 4096) * 1024 + threadIdx.x * 4;
        float4 v = *(const float4*)(qkv_w + i);
        ushort4 o;
        o.x = f2bf(v.x); o.y = f2bf(v.y); o.z = f2bf(v.z); o.w = f2bf(v.w);
        *(ushort4*)(wh + i) = o;
    } else if (blk < 7168) {
        int i = (blk - 6144) * 1024 + threadIdx.x * 4;
        float4 v = *(const float4*)(qkv_w + 2097152 + i);
        ushort4 h, l;
        h.x = f2bf(v.x); l.x = f2bf(v.x - bf2f(h.x));
        h.y = f2bf(v.y); l.y = f2bf(v.y - bf2f(h.y));
        h.z = f2bf(v.z); l.z = f2bf(v.z - bf2f(h.z));
        h.w = f2bf(v.w); l.w = f2bf(v.w - bf2f(h.w));
        *(ushort4*)(wh + 2097152 + i) = h;
        *(ushort4*)(wlv + i) = l;
    } else if (blk < 8192) {
        const int wave = threadIdx.x >> 6;
        const int lane = threadIdx.x & 63;
        const int row  = (blk - 7168) * 4 + wave;
        const int NR = NB * (SEQ - 1);
        if (row >= NR) return;
        const int b = row / (SEQ - 1);
        const int j = row - b * (SEQ - 1);
        const float* x0 = x + ((size_t)(b * SEQ + j)) * DIM;
        const float* x1 = x0 + DIM;
        float sum = 0.f;
        #pragma unroll
        for (int q = 0; q < 4; ++q) {
            int idx = q * 256 + lane * 4;
            float4 a = *(const float4*)(x0 + idx);
            float4 c = *(const float4*)(x1 + idx);
            float dx = c.x-a.x, dy = c.y-a.y, dz = c.z-a.z, dw = c.w-a.w;
            sum += dx*dx + dy*dy + dz*dz + dw*dw;
        }
        #pragma unroll
        for (int off = 32; off > 0; off >>= 1) sum += __shfl_down(sum, off);
        if (lane == 0) {
            float mag = sqrtf(sum);
            sbuf[row]   = tanhf(mag);
            invbuf[row] = 1.0f / fmaxf(mag, 1e-8f);
        }
    } else {
        int i = (blk - 8192) * 1024 + threadIdx.x * 4;
        float4 v = *(const float4*)(out_w + i);
        ushort4 h, l;
        h.x = f2bf(v.x); l.x = f2bf(v.x - bf2f(h.x));
        h.y = f2bf(v.y); l.y = f2bf(v.y - bf2f(h.y));
        h.z = f2bf(v.z); l.z = f2bf(v.z - bf2f(h.z));
        h.w = f2bf(v.w); l.w = f2bf(v.w - bf2f(h.w));
        *(ushort4*)(owh + i) = h;
        *(ushort4*)(owl + i) = l;
    }
}

// ---------------------------------------------------------------------------
// traj combine body (window <= 8), one block per (b, pos)
// ---------------------------------------------------------------------------
__device__ __forceinline__ void traj_body(
    int bp, const float* __restrict__ x, const float* __restrict__ sbuf,
    const float* __restrict__ invbuf, float* __restrict__ traj_out)
{
    const int b  = bp >> 11;
    const int p  = bp & (SEQ - 1);
    int ws = p - 8; if (ws < 0) ws = 0;
    const int wlen = p - ws;
    const float wsz = (float)((p - ws) > 1 ? (p - ws) : 1);
    const int base = b * (SEQ - 1) + ws;

    float Z = 0.f;
    for (int t = 0; t < wlen; ++t)
        Z += sbuf[base + t] * ((float)(t + 1) / wsz);
    const float scale = 1.0f / fmaxf(Z, 1e-8f);

    const int d0 = threadIdx.x * 4;
    const float* xb = x + ((size_t)(b * SEQ + ws)) * DIM + d0;
    float4 prev = *(const float4*)xb;
    float4 acc = make_float4(0.f,0.f,0.f,0.f);
    for (int t = 0; t < wlen; ++t) {
        xb += DIM;
        float4 cur = *(const float4*)xb;
        float cc = sbuf[base + t] * ((float)(t + 1) / wsz) * invbuf[base + t] * scale;
        acc.x += cc * (cur.x - prev.x);
        acc.y += cc * (cur.y - prev.y);
        acc.z += cc * (cur.z - prev.z);
        acc.w += cc * (cur.w - prev.w);
        prev = cur;
    }
    *(float4*)(traj_out + (size_t)bp * DIM + d0) = acc;
}

// ---------------------------------------------------------------------------
// MFMA bf16 GEMM body: C[M,N] = A[M,1024] @ B[N,1024]^T.  Tile 128 x BN,
// BK=32, 4 waves 2x2 (wave tile 64 x BN/2), 16x16x32 MFMAs.
// SPLIT=1: A ~= Ah+Al, B ~= Bh+Bl; C = Ah·Bh + Ah·Bl + Al·Bh (fp32-ish).
// EPI=0: fp32 store to cout (ldc).
// EPI=2 (v^T): bf16 store to qwb[b][m][token&2047]  (vbt layout [B,1024,S]).
// ---------------------------------------------------------------------------
template<int SPLIT, int EPI, int BN>
__device__ __forceinline__ void gemm_body(
    int bx, int by, char* smem,
    const ushort* __restrict__ Ah, const ushort* __restrict__ Al,
    const ushort* __restrict__ Bh, const ushort* __restrict__ Bl,
    float* __restrict__ cout, int ldc,
    ushort* __restrict__ qwb)
{
    constexpr int JT   = BN / 32;                    // N frags per wave
    constexpr int BSZ  = BN * 64;                    // B tile bytes (BN rows x 64B)
    constexpr int HALF = 8192 + BSZ;                 // one precision level (A+B)
    const int tid = threadIdx.x;
    const int l = tid & 63;
    const int w = tid >> 6;
    const int wm = w >> 1, wn = w & 1;
    const int n0 = bx * BN;
    const int m0 = by * 128;

    char* a_h = smem;
    char* b_h = smem + 8192;
    char* a_l = smem + HALF;
    char* b_l = smem + HALF + 8192;

    const int srowA = 32 * w + (l >> 2);
    const int srowB = (BN == 128 ? 32 * w : 16 * w) + (l >> 2);
    const int scol  = (l & 3) * 8;
    const ushort* Ahg = Ah + (size_t)(m0 + srowA) * 1024 + scol;
    const ushort* Bhg = Bh + (size_t)(n0 + srowB) * 1024 + scol;
    const ushort* Alg = SPLIT ? Al + (size_t)(m0 + srowA) * 1024 + scol : nullptr;
    const ushort* Blg = SPLIT ? Bl + (size_t)(n0 + srowB) * 1024 + scol : nullptr;

    floatx4 acc[4][JT] = {};
    const int fr = l & 15;
    const int fq = (l >> 4) * 16;

    for (int kb = 0; kb < 1024; kb += 32) {
        if (kb) __syncthreads();
        gload16(Ahg + kb,             a_h + w*2048);
        gload16(Ahg + kb + 16*1024,   a_h + w*2048 + 1024);
        if (BN == 128) {
            gload16(Bhg + kb,             b_h + w*2048);
            gload16(Bhg + kb + 16*1024,   b_h + w*2048 + 1024);
        } else {
            gload16(Bhg + kb,             b_h + w*1024);
        }
        if (SPLIT) {
            gload16(Alg + kb,           a_l + w*2048);
            gload16(Alg + kb + 16*1024, a_l + w*2048 + 1024);
            if (BN == 128) {
                gload16(Blg + kb,           b_l + w*2048);
                gload16(Blg + kb + 16*1024, b_l + w*2048 + 1024);
            } else {
                gload16(Blg + kb,           b_l + w*1024);
            }
        }
        __syncthreads();
        short8 fah[4], fbh[JT], fal[4], fbl[JT];
        #pragma unroll
        for (int t = 0; t < 4; ++t) {
            fah[t] = *(const short8*)(a_h + ((wm*64 + t*16 + fr) << 6) + fq);
            if (SPLIT)
                fal[t] = *(const short8*)(a_l + ((wm*64 + t*16 + fr) << 6) + fq);
        }
        #pragma unroll
        for (int t = 0; t < JT; ++t) {
            fbh[t] = *(const short8*)(b_h + ((wn*(BN/2) + t*16 + fr) << 6) + fq);
            if (SPLIT)
                fbl[t] = *(const short8*)(b_l + ((wn*(BN/2) + t*16 + fr) << 6) + fq);
        }
        #pragma unroll
        for (int it = 0; it < 4; ++it)
            #pragma unroll
            for (int jt = 0; jt < JT; ++jt) {
                acc[it][jt] = __builtin_amdgcn_mfma_f32_16x16x32_bf16(
                    fah[it], fbh[jt], acc[it][jt], 0, 0, 0);
                if (SPLIT) {
                    acc[it][jt] = __builtin_amdgcn_mfma_f32_16x16x32_bf16(
                        fah[it], fbl[jt], acc[it][jt], 0, 0, 0);
                    acc[it][jt] = __builtin_amdgcn_mfma_f32_16x16x32_bf16(
                        fal[it], fbh[jt], acc[it][jt], 0, 0, 0);
                }
            }
    }

    const int row0 = (l >> 4) * 4;   // C: row=(l>>4)*4+reg, col=l&15
    const int col  = l & 15;

    if (EPI == 0) {
        #pragma unroll
        for (int it = 0; it < 4; ++it)
            #pragma unroll
            for (int jt = 0; jt < JT; ++jt)
                #pragma unroll
                for (int r = 0; r < 4; ++r) {
                    int gm = m0 + wm*64 + it*16 + row0 + r;
                    int gn = n0 + wn*(BN/2) + jt*16 + col;
                    cout[(size_t)gm * ldc + gn] = acc[it][jt][r];
                }
    } else {
        // transposed v store: rows m = h*64+d, cols n = token
        #pragma unroll
        for (int it = 0; it < 4; ++it)
            #pragma unroll
            for (int jt = 0; jt < JT; ++jt)
                #pragma unroll
                for (int r = 0; r < 4; ++r) {
                    int md = m0 + wm*64 + it*16 + row0 + r;
                    int t  = n0 + wn*(BN/2) + jt*16 + col;
                    int bb = t >> 11, ss = t & (SEQ - 1);
                    qwb[((size_t)bb << 21) + (size_t)md * SEQ + ss] = f2bf(acc[it][jt][r]);
                }
    }
}

// ---------------------------------------------------------------------------
// qk GEMM (plain bf16, BN=128) with FUSED splat epilogue (never materializes
// q/k). Wave tile = 64 tokens x one full head. After the K-loop:
//  1) store wave's 64x64 tile bf16 to LDS, XOR-swizzled 16B blocks;
//  2) lane = token: iterate logical col-octets cb (physical block cb^(l&7)):
//     q via ds_read_b128; centers via WAVE-UNIFORM broadcast float4 reads;
//     dq[sp] += (q-c)^2 running accumulators (no qv[64] array);
//  3) w_sp = exp(-0.5*dq/s^2)*sigmoid(amp) with per-block precomputed Pr.
// ---------------------------------------------------------------------------
__device__ __forceinline__ void qk_splat_body(
    int bx, int by, char* smem,
    const ushort* __restrict__ Ah, const ushort* __restrict__ Bh,
    ushort* __restrict__ qwb, ushort* __restrict__ kwb,
    const float* __restrict__ centers, const float* __restrict__ lscales,
    const float* __restrict__ amps)
{
    const int tid = threadIdx.x;
    const int l = tid & 63;
    const int w = tid >> 6;
    const int wm = w >> 1, wn = w & 1;
    const int n0 = bx * 128;
    const int m0 = by * 128;
    char* a_h = smem;
    char* b_h = smem + 8192;
    float* Cst = (float*)(smem + 32768);   // [2 heads][16 sp][64] f32, 8KB
    float* Pr  = (float*)(smem + 40960);   // [2 heads][{coef,amp}][16]

    const int hb = (n0 & 1023) >> 6;       // first head of this block
    {
        const float* src = centers + (size_t)hb * 1024;
        float4 v0 = *(const float4*)(src + tid*8);
        float4 v1 = *(const float4*)(src + tid*8 + 4);
        *(float4*)(Cst + tid*8)     = v0;
        *(float4*)(Cst + tid*8 + 4) = v1;
    }
    if (tid < 32) {
        int hl = tid >> 4, sp = tid & 15;
        float s2 = __expf(2.f * lscales[(hb + hl)*16 + sp]);
        Pr[hl*32 + sp]      = -0.5f / s2;
        Pr[hl*32 + 16 + sp] = 1.f / (1.f + __expf(-amps[(hb + hl)*16 + sp]));
    }

    const int srow = 32 * w + (l >> 2);
    const int scol = (l & 3) * 8;
    const ushort* Ahg = Ah + (size_t)(m0 + srow) * 1024 + scol;
    const ushort* Bhg = Bh + (size_t)(n0 + srow) * 1024 + scol;

    floatx4 acc[4][4] = {};
    const int fr = l & 15;
    const int fq = (l >> 4) * 16;

    for (int kb = 0; kb < 1024; kb += 32) {
        if (kb) __syncthreads();
        gload16(Ahg + kb,             a_h + w*2048);
        gload16(Ahg + kb + 16*1024,   a_h + w*2048 + 1024);
        gload16(Bhg + kb,             b_h + w*2048);
        gload16(Bhg + kb + 16*1024,   b_h + w*2048 + 1024);
        __syncthreads();
        short8 fah[4], fbh[4];
        #pragma unroll
        for (int t = 0; t < 4; ++t) {
            fah[t] = *(const short8*)(a_h + ((wm*64 + t*16 + fr) << 6) + fq);
            fbh[t] = *(const short8*)(b_h + ((wn*64 + t*16 + fr) << 6) + fq);
        }
        #pragma unroll
        for (int it = 0; it < 4; ++it)
            #pragma unroll
            for (int jt = 0; jt < 4; ++jt)
                acc[it][jt] = __builtin_amdgcn_mfma_f32_16x16x32_bf16(
                    fah[it], fbh[jt], acc[it][jt], 0, 0, 0);
    }

    // ---- fused splat epilogue ----
    __syncthreads();                       // staging dead; Cst/Pr ready
    const int row0 = (l >> 4) * 4;
    const int col  = l & 15;
    ushort* qt = (ushort*)(smem + w*8192); // wave's 64x64 bf16 tile

    #pragma unroll
    for (int it = 0; it < 4; ++it)
        #pragma unroll
        for (int jt = 0; jt < 4; ++jt)
            #pragma unroll
            for (int r = 0; r < 4; ++r) {
                int tok = it*16 + row0 + r;
                int c   = jt*16 + col;
                qt[tok*64 + ((((c >> 3) ^ (tok & 7)) << 3) | (c & 7))] =
                    f2bf(acc[it][jt][r]);
            }

    const float* cw  = Cst + wn*1024;      // this wave's head's centers
    const float* prc = Pr  + wn*32;
    float dq[16];
    #pragma unroll
    for (int sp = 0; sp < 16; ++sp) dq[sp] = 0.f;

    #pragma unroll
    for (int cb = 0; cb < 8; ++cb) {       // logical col-octet
        short8 v = *(const short8*)(qt + l*64 + ((cb ^ (l & 7)) << 3));
        float qv8[8];
        #pragma unroll
        for (int i = 0; i < 8; ++i) qv8[i] = bf2f((ushort)v[i]);
        const float* cbp = cw + cb*8;      // wave-uniform broadcast reads
        #pragma unroll
        for (int sp = 0; sp < 16; ++sp) {
            float4 c0 = *(const float4*)(cbp + sp*64);
            float4 c1 = *(const float4*)(cbp + sp*64 + 4);
            float t0 = qv8[0] - c0.x; dq[sp] = fmaf(t0, t0, dq[sp]);
            float t1 = qv8[1] - c0.y; dq[sp] = fmaf(t1, t1, dq[sp]);
            float t2 = qv8[2] - c0.z; dq[sp] = fmaf(t2, t2, dq[sp]);
            float t3 = qv8[3] - c0.w; dq[sp] = fmaf(t3, t3, dq[sp]);
            float t4 = qv8[4] - c1.x; dq[sp] = fmaf(t4, t4, dq[sp]);
            float t5 = qv8[5] - c1.y; dq[sp] = fmaf(t5, t5, dq[sp]);
            float t6 = qv8[6] - c1.z; dq[sp] = fmaf(t6, t6, dq[sp]);
            float t7 = qv8[7] - c1.w; dq[sp] = fmaf(t7, t7, dq[sp]);
        }
    }

    const int hh = hb + wn;
    const int tg = m0 + wm*64 + l;
    const int bb = tg >> 11, ss = tg & (SEQ - 1);
    ushort* obuf = (n0 < 1024) ? qwb : kwb;
    ushort o16[16];
    #pragma unroll
    for (int sp = 0; sp < 16; ++sp)
        o16[sp] = f2bf(__expf(dq[sp] * prc[sp]) * prc[16 + sp]);
    ushort* op = obuf + (((size_t)(bb*NH + hh))*SEQ + ss)*16;
    *(short8*)(op)     = *(short8*)(o16);
    *(short8*)(op + 8) = *(short8*)(o16 + 8);
}

// Dispatch B: v^T GEMM (split, BN=64, 512 blocks) + traj[0,3072)
__global__ __launch_bounds__(256) void gemmV_traj_kernel(
    const ushort* __restrict__ Ah, const ushort* __restrict__ Al,
    const ushort* __restrict__ Bh, const ushort* __restrict__ Bl,
    ushort* __restrict__ vbt,
    const float* __restrict__ x, const float* __restrict__ sbuf,
    const float* __restrict__ invbuf, float* __restrict__ traj_out)
{
    __shared__ __align__(16) char smem[2 * (8192 + 64*64)];
    const int blk = blockIdx.x;
    if (blk < 512) {
        gemm_body<1,2,64>(blk & 63, blk >> 6, smem, Ah, Al, Bh, Bl,
                          nullptr, 0, vbt);
    } else {
        traj_body(blk - 512, x, sbuf, invbuf, traj_out);
    }
}

// Dispatch C: q/k GEMM + fused splat (512 blocks) + traj[3072,4096)
__global__ __launch_bounds__(256) void qksplat_traj_kernel(
    const ushort* __restrict__ Ah, const ushort* __restrict__ Bh,
    ushort* __restrict__ qwb, ushort* __restrict__ kwb,
    const float* __restrict__ centers, const float* __restrict__ lscales,
    const float* __restrict__ amps,
    const float* __restrict__ x, const float* __restrict__ sbuf,
    const float* __restrict__ invbuf, float* __restrict__ traj_out)
{
    __shared__ __align__(16) char smem[41216];
    const int blk = blockIdx.x;
    if (blk < 512) {
        qk_splat_body(blk & 15, blk >> 4, smem, Ah, Bh,
                      qwb, kwb, centers, lscales, amps);
    } else {
        traj_body(blk - 512 + 3072, x, sbuf, invbuf, traj_out);
    }
}

// Dispatch F: out GEMM (split, BN=64, fp32 out)
__global__ __launch_bounds__(256) void gemmO_kernel(
    const ushort* __restrict__ Ah, const ushort* __restrict__ Al,
    const ushort* __restrict__ Bh, const ushort* __restrict__ Bl,
    float* __restrict__ cout)
{
    __shared__ __align__(16) char smem[2 * (8192 + 64*64)];
    gemm_body<1,0,64>(blockIdx.x, blockIdx.y, smem, Ah, Al, Bh, Bl,
                      cout, 1024, nullptr);
}

// ---------------------------------------------------------------------------
// MFMA flash attention, v3: all-register P (no P LDS round-trip).
// 256 threads / 4 waves (qh, kh); QK quadrant via 1x mfma_32x32x16, exp,
// in-register redistribution to PV A-fragment via cvt_pk + permlane32_swap;
// PV via 4x mfma_32x32x16 from xor-swizzled double-buffered V tile.
// One barrier per 64-key tile; kh-partials combined through LDS at the end.
// ---------------------------------------------------------------------------
__global__ __launch_bounds__(256, 4) void attn_kernel(
    const ushort* __restrict__ qw, const ushort* __restrict__ kw,
    const ushort* __restrict__ vbt, ushort* __restrict__ hoh, ushort* __restrict__ hol)
{
    // [0,16K): V^T double buffer (2 x 8KB, [64 d][8 blk of 16B], blk^=(d&7))
    // [16K,16K+512): z combine buffer
    __shared__ __align__(16) char smem[16384 + 512];
    const int tid = threadIdx.x;
    const int l   = tid & 63;
    const int w   = tid >> 6;        // 0..3
    const int qh  = w >> 1;
    const int kh  = w & 1;
    const int l31 = l & 31;
    const int hi  = l >> 5;
    const int bh = blockIdx.y;
    const int b = bh >> 4;
    const int h = bh & 15;
    const int s0 = blockIdx.x * 64;

    // Q fragment (B operand): query s0+qh*32+l31, splat k = hi*8..+8
    short8 qf = *(const short8*)(qw + ((size_t)bh*SEQ + s0 + qh*32 + l31)*16 + hi*8);

    // K fragment source (A operand), direct from global (L2-hot)
    const ushort* kfp = kw + ((size_t)bh*SEQ + kh*32 + l31)*16 + hi*8;
    const ushort* vtb = vbt + ((size_t)(b*1024 + h*64))*SEQ;

    // V stage sources (pre-swizzled global addr -> linear LDS dest)
    const int dA = w*16 + (l >> 3);
    const int dB = dA + 8;
    const ushort* vsA = vtb + (size_t)dA*SEQ + ((l & 7) ^ (dA & 7))*8;
    const ushort* vsB = vtb + (size_t)dB*SEQ + ((l & 7) ^ (dB & 7))*8;

    floatx16 acc0 = {}, acc1 = {};
    floatx16 zero16 = {};
    float zpart = 0.f;

    // prologue: stage tile 0 into buf 0, load kf for tile 0
    gload16(vsA, smem + w*2048);
    gload16(vsB, smem + w*2048 + 1024);
    short8 kf = *(const short8*)kfp;

    for (int jt = 0; jt < 32; ++jt) {
        __syncthreads();   // drains own vmcnt/lgkm: stage(jt) landed, reads of buf^1 done
        char* bufn = smem + ((jt + 1) & 1)*8192;
        if (jt < 31) {
            gload16(vsA + (jt + 1)*64, bufn + w*2048);
            gload16(vsB + (jt + 1)*64, bufn + w*2048 + 1024);
        }
        // QK^T quadrant: C[key][query], key=(r&3)+8*(r>>2)+4*hi (+kh*32), q=l31 (+qh*32)
        floatx16 sc = __builtin_amdgcn_mfma_f32_32x32x16_bf16(kf, qf, zero16, 0, 0, 0);
        if (jt < 31) kf = *(const short8*)(kfp + (jt + 1)*1024);

        float e[16];
        #pragma unroll
        for (int r = 0; r < 16; ++r) e[r] = __expf(sc[r]);
        float zs = 0.f;
        #pragma unroll
        for (int r = 0; r < 16; ++r) zs += e[r];
        zpart += zs;

        // pack to PV A-fragments (lane q=l31, k=8*hi+0..7)
        unsigned p0 = cvtpk(e[0],  e[1]),  p1 = cvtpk(e[2],  e[3]);
        unsigned p2 = cvtpk(e[4],  e[5]),  p3 = cvtpk(e[6],  e[7]);
        unsigned p4 = cvtpk(e[8],  e[9]),  p5 = cvtpk(e[10], e[11]);
        unsigned p6 = cvtpk(e[12], e[13]), p7 = cvtpk(e[14], e[15]);
        plswap(p0, p2); plswap(p1, p3);   // kseg0: keys kh*32 + 0..15
        plswap(p4, p6); plswap(p5, p7);   // kseg1: keys kh*32 + 16..31
        union { unsigned u[4]; short8 s; } ua, ub;
        ua.u[0] = p0; ua.u[1] = p1; ua.u[2] = p2; ua.u[3] = p3;
        ub.u[0] = p4; ub.u[1] = p5; ub.u[2] = p6; ub.u[3] = p7;

        // PV: O[q][d], V as B operand (lane: d col = l31 (+32*dt), 8 tokens)
        const ushort* buf = (const ushort*)(smem + (jt & 1)*8192);
        #pragma unroll
        for (int dt = 0; dt < 2; ++dt) {
            int row = dt*32 + l31;
            const ushort* vr = buf + row*64;
            int bk0 = (kh*4 + hi)     ^ (row & 7);
            int bk1 = (kh*4 + 2 + hi) ^ (row & 7);
            short8 vb0 = *(const short8*)(vr + bk0*8);
            short8 vb1 = *(const short8*)(vr + bk1*8);
            if (dt == 0) {
                acc0 = __builtin_amdgcn_mfma_f32_32x32x16_bf16(ua.s, vb0, acc0, 0, 0, 0);
                acc0 = __builtin_amdgcn_mfma_f32_32x32x16_bf16(ub.s, vb1, acc0, 0, 0, 0);
            } else {
                acc1 = __builtin_amdgcn_mfma_f32_32x32x16_bf16(ua.s, vb0, acc1, 0, 0, 0);
                acc1 = __builtin_amdgcn_mfma_f32_32x32x16_bf16(ub.s, vb1, acc1, 0, 0, 0);
            }
        }
    }

    __syncthreads();   // drain everything before aliasing V buffers

    float* cb = (float*)smem;              // [qh*32+q][64 d] f32 = 16KB
    float* zb = (float*)(smem + 16384);    // [kh][64] f32 = 512B

    // z across hi halves: both halves end with total for their q
    unsigned za = __float_as_uint(zpart), zc = za;
    plswap(za, zc);
    float zq = __uint_as_float(za) + __uint_as_float(zc);
    if (l31 == l) zb[kh*64 + qh*32 + l31] = zq;   // lanes 0..31 only

    if (kh) {
        #pragma unroll
        for (int r = 0; r < 16; ++r) {
            int q = (r & 3) + 8*(r >> 2) + 4*hi;
            cb[(qh*32 + q)*64 + l31]      = acc0[r];
            cb[(qh*32 + q)*64 + 32 + l31] = acc1[r];
        }
    }
    __syncthreads();
    if (!kh) {
        #pragma unroll
        for (int r = 0; r < 16; ++r) {
            int q = (r & 3) + 8*(r >> 2) + 4*hi;
            float zt = zb[qh*32 + q] + zb[64 + qh*32 + q];
            float inv = 1.0f / zt;
            int s = s0 + qh*32 + q;
            size_t base = ((size_t)(b*SEQ + s))*1024 + h*64;
            float v0 = (acc0[r] + cb[(qh*32 + q)*64 + l31])      * inv;
            float v1 = (acc1[r] + cb[(qh*32 + q)*64 + 32 + l31]) * inv;
            ushort h0 = f2bf(v0);
            ushort h1 = f2bf(v1);
            hoh[base + l31]      = h0;
            hol[base + l31]      = f2bf(v0 - bf2f(h0));
            hoh[base + 32 + l31] = h1;
            hol[base + 32 + l31] = f2bf(v1 - bf2f(h1));
        }
    }
}

// ---------------------------------------------------------------------------
extern "C" void kernel_launch(void* const* d_in, const int* in_sizes, int n_in,
                              void* d_out, int out_size, void* d_ws, size_t ws_size,
                              hipStream_t stream)
{
    const float* x       = (const float*)d_in[0];
    const float* qkv_w   = (const float*)d_in[1];
    const float* out_w   = (const float*)d_in[2];
    const float* centers = (const float*)d_in[3];
    const float* lscales = (const float*)d_in[4];
    const float* amps    = (const float*)d_in[5];
    float* out  = (float*)d_out;                      // [B,S,D]
    float* traj = out + (size_t)NB*SEQ*DIM;           // [B,S,D]

    char* wsb = (char*)d_ws;                          // 40.03 MB total
    ushort* xh   = (ushort*)(wsb);                    // [0,8) MB  bf16 x hi
    ushort* xl   = (ushort*)(wsb + (8u<<20));         // [8,16) MB bf16 x lo
    ushort* wh   = (ushort*)(wsb + (16u<<20));        // [16,22) MB qkv_w hi (3072x1024)
    ushort* wlv  = (ushort*)(wsb + (22u<<20));        // [22,24) MB v-weight lo
    ushort* vbt  = (ushort*)(wsb + (24u<<20));        // [24,32) MB v^T bf16 [B,1024,S]
    ushort* owh  = (ushort*)(wsb + (32u<<20));        // [32,34) MB out_w hi
    ushort* owl  = (ushort*)(wsb + (34u<<20));        // [34,36) MB out_w lo
    ushort* qwbh = (ushort*)(wsb + (36u<<20));        // [36,38) MB q splat weights
    ushort* kwbh = (ushort*)(wsb + (38u<<20));        // [38,40) MB k splat weights
    float*  sbuf = (float*)(wsb + (40u<<20));         // 16 KB
    float*  invb = sbuf + 4096;                       // 16 KB
    // aliases (dead by the time they're written):
    ushort* hoh  = xh;                                // attn out hi (xh dead after C)
    ushort* hol  = xl;                                // attn out lo (xl dead after B)

    // A: input conversions + traj stats + out_w split
    front_kernel<<<9216, 256, 0, stream>>>(
        x, qkv_w, out_w, xh, xl, wh, wlv, owh, owl, sbuf, invb);
    // B: v^T GEMM (split) + traj[0,3072)
    gemmV_traj_kernel<<<3584, 256, 0, stream>>>(
        wh + 2048*1024, wlv, xh, xl, vbt, x, sbuf, invb, traj);
    // C: qk GEMM + fused splat + traj[3072,4096)
    qksplat_traj_kernel<<<1536, 256, 0, stream>>>(
        xh, wh, qwbh, kwbh, centers, lscales, amps, x, sbuf, invb, traj);
    // attention
    attn_kernel<<<dim3(32, 32), 256, 0, stream>>>(qwbh, kwbh, vbt, hoh, hol);
    // out = ho @ out_w^T (split, fp32 out)
    gemmO_kernel<<<dim3(16, 32), 256, 0, stream>>>(hoh, hol, owh, owl, out);
}

// Round 9
// 232.902 us; speedup vs baseline: 1.0986x; 1.0034x over previous
//
#include <hip/hip_runtime.h>
#include <math.h>

// Problem constants (B=2, S=2048, D=1024, H=16, hd=64, K=16)
#define SEQ 2048
#define DIM 1024
#define NB  2
#define NH  16

typedef __attribute__((ext_vector_type(8))) short short8;
typedef __attribute__((ext_vector_type(4))) float floatx4;
typedef __attribute__((ext_vector_type(16))) float floatx16;

__device__ __forceinline__ ushort f2bf(float f) {
    unsigned u = __float_as_uint(f);
    return (ushort)((u + 0x7FFFu + ((u >> 16) & 1u)) >> 16);
}
__device__ __forceinline__ float bf2f(ushort h) {
    return __uint_as_float(((unsigned)h) << 16);
}
// async global->LDS, 16B per lane; LDS dest = wave-uniform base + lane*16
__device__ __forceinline__ void gload16(const void* g, char* lds_base) {
    __builtin_amdgcn_global_load_lds(
        (const __attribute__((address_space(1))) void*)g,
        (__attribute__((address_space(3))) void*)lds_base, 16, 0, 0);
}
// packed f32x2 -> bf16x2 (RNE), low word = a
__device__ __forceinline__ unsigned cvtpk(float a, float b) {
    unsigned r;
    asm("v_cvt_pk_bf16_f32 %0, %1, %2" : "=v"(r) : "v"(a), "v"(b));
    return r;
}
// swap: a -> [a.lo32 | b.lo32], b -> [a.hi32 | b.hi32]
__device__ __forceinline__ void plswap(unsigned &a, unsigned &b) {
    asm("v_permlane32_swap_b32 %0, %1" : "+v"(a), "+v"(b));
}

// ---------------------------------------------------------------------------
// Dispatch A: everything that depends only on kernel inputs.
//  blocks [0,4096):    x fp32 -> xh + xl (split)
//  blocks [4096,6144): qkv_w q/k rows -> wh (hi only)
//  blocks [6144,7168): qkv_w v rows   -> wh+2M (hi) + wlv (lo)
//  blocks [7168,8192): traj stats (4 diff-rows per block)
//  blocks [8192,9216): out_w -> owh + owl (split)
// ---------------------------------------------------------------------------
__global__ __launch_bounds__(256) void front_kernel(
    const float* __restrict__ x, const float* __restrict__ qkv_w,
    const float* __restrict__ out_w,
    ushort* __restrict__ xh, ushort* __restrict__ xl,
    ushort* __restrict__ wh, ushort* __restrict__ wlv,
    ushort* __restrict__ owh, ushort* __restrict__ owl,
    float* __restrict__ sbuf, float* __restrict__ invbuf)
{
    const int blk = blockIdx.x;
    if (blk < 4096) {
        int i = blk * 1024 + threadIdx.x * 4;
        float4 v = *(const float4*)(x + i);
        ushort4 h, l;
        h.x = f2bf(v.x); l.x = f2bf(v.x - bf2f(h.x));
        h.y = f2bf(v.y); l.y = f2bf(v.y - bf2f(h.y));
        h.z = f2bf(v.z); l.z = f2bf(v.z - bf2f(h.z));
        h.w = f2bf(v.w); l.w = f2bf(v.w - bf2f(h.w));
        *(ushort4*)(xh + i) = h;
        *(ushort4*)(xl + i) = l;
    } else if (blk < 6144) {
        int i = (blk - 4096) * 1024 + threadIdx.x * 4;
        float4 v = *(const float4*)(qkv_w + i);
        ushort4 o;
        o.x = f2bf(v.x); o.y = f2bf(v.y); o.z = f2bf(v.z); o.w = f2bf(v.w);
        *(ushort4*)(wh + i) = o;
    } else if (blk < 7168) {
        int i = (blk - 6144) * 1024 + threadIdx.x * 4;
        float4 v = *(const float4*)(qkv_w + 2097152 + i);
        ushort4 h, l;
        h.x = f2bf(v.x); l.x = f2bf(v.x - bf2f(h.x));
        h.y = f2bf(v.y); l.y = f2bf(v.y - bf2f(h.y));
        h.z = f2bf(v.z); l.z = f2bf(v.z - bf2f(h.z));
        h.w = f2bf(v.w); l.w = f2bf(v.w - bf2f(h.w));
        *(ushort4*)(wh + 2097152 + i) = h;
        *(ushort4*)(wlv + i) = l;
    } else if (blk < 8192) {
        const int wave = threadIdx.x >> 6;
        const int lane = threadIdx.x & 63;
        const int row  = (blk - 7168) * 4 + wave;
        const int NR = NB * (SEQ - 1);
        if (row >= NR) return;
        const int b = row / (SEQ - 1);
        const int j = row - b * (SEQ - 1);
        const float* x0 = x + ((size_t)(b * SEQ + j)) * DIM;
        const float* x1 = x0 + DIM;
        float sum = 0.f;
        #pragma unroll
        for (int q = 0; q < 4; ++q) {
            int idx = q * 256 + lane * 4;
            float4 a = *(const float4*)(x0 + idx);
            float4 c = *(const float4*)(x1 + idx);
            float dx = c.x-a.x, dy = c.y-a.y, dz = c.z-a.z, dw = c.w-a.w;
            sum += dx*dx + dy*dy + dz*dz + dw*dw;
        }
        #pragma unroll
        for (int off = 32; off > 0; off >>= 1) sum += __shfl_down(sum, off);
        if (lane == 0) {
            float mag = sqrtf(sum);
            sbuf[row]   = tanhf(mag);
            invbuf[row] = 1.0f / fmaxf(mag, 1e-8f);
        }
    } else {
        int i = (blk - 8192) * 1024 + threadIdx.x * 4;
        float4 v = *(const float4*)(out_w + i);
        ushort4 h, l;
        h.x = f2bf(v.x); l.x = f2bf(v.x - bf2f(h.x));
        h.y = f2bf(v.y); l.y = f2bf(v.y - bf2f(h.y));
        h.z = f2bf(v.z); l.z = f2bf(v.z - bf2f(h.z));
        h.w = f2bf(v.w); l.w = f2bf(v.w - bf2f(h.w));
        *(ushort4*)(owh + i) = h;
        *(ushort4*)(owl + i) = l;
    }
}

// ---------------------------------------------------------------------------
// traj combine body (window <= 8), one block per (b, pos)
// ---------------------------------------------------------------------------
__device__ __forceinline__ void traj_body(
    int bp, const float* __restrict__ x, const float* __restrict__ sbuf,
    const float* __restrict__ invbuf, float* __restrict__ traj_out)
{
    const int b  = bp >> 11;
    const int p  = bp & (SEQ - 1);
    int ws = p - 8; if (ws < 0) ws = 0;
    const int wlen = p - ws;
    const float wsz = (float)((p - ws) > 1 ? (p - ws) : 1);
    const int base = b * (SEQ - 1) + ws;

    float Z = 0.f;
    for (int t = 0; t < wlen; ++t)
        Z += sbuf[base + t] * ((float)(t + 1) / wsz);
    const float scale = 1.0f / fmaxf(Z, 1e-8f);

    const int d0 = threadIdx.x * 4;
    const float* xb = x + ((size_t)(b * SEQ + ws)) * DIM + d0;
    float4 prev = *(const float4*)xb;
    float4 acc = make_float4(0.f,0.f,0.f,0.f);
    for (int t = 0; t < wlen; ++t) {
        xb += DIM;
        float4 cur = *(const float4*)xb;
        float cc = sbuf[base + t] * ((float)(t + 1) / wsz) * invbuf[base + t] * scale;
        acc.x += cc * (cur.x - prev.x);
        acc.y += cc * (cur.y - prev.y);
        acc.z += cc * (cur.z - prev.z);
        acc.w += cc * (cur.w - prev.w);
        prev = cur;
    }
    *(float4*)(traj_out + (size_t)bp * DIM + d0) = acc;
}

// ---------------------------------------------------------------------------
// MFMA bf16 GEMM body: C[M,N] = A[M,1024] @ B[N,1024]^T.  Tile 128 x BN,
// BK=32, 4 waves 2x2 (wave tile 64 x BN/2), 16x16x32 MFMAs.
// SPLIT=1: A ~= Ah+Al, B ~= Bh+Bl; C = Ah·Bh + Ah·Bl + Al·Bh (fp32-ish).
// EPI=0: fp32 store to cout (ldc).
// EPI=2 (v^T): bf16 store to qwb[b][m][token&2047]  (vbt layout [B,1024,S]).
// ---------------------------------------------------------------------------
template<int SPLIT, int EPI, int BN>
__device__ __forceinline__ void gemm_body(
    int bx, int by, char* smem,
    const ushort* __restrict__ Ah, const ushort* __restrict__ Al,
    const ushort* __restrict__ Bh, const ushort* __restrict__ Bl,
    float* __restrict__ cout, int ldc,
    ushort* __restrict__ qwb)
{
    constexpr int JT   = BN / 32;                    // N frags per wave
    constexpr int BSZ  = BN * 64;                    // B tile bytes (BN rows x 64B)
    constexpr int HALF = 8192 + BSZ;                 // one precision level (A+B)
    const int tid = threadIdx.x;
    const int l = tid & 63;
    const int w = tid >> 6;
    const int wm = w >> 1, wn = w & 1;
    const int n0 = bx * BN;
    const int m0 = by * 128;

    char* a_h = smem;
    char* b_h = smem + 8192;
    char* a_l = smem + HALF;
    char* b_l = smem + HALF + 8192;

    const int srowA = 32 * w + (l >> 2);
    const int srowB = (BN == 128 ? 32 * w : 16 * w) + (l >> 2);
    const int scol  = (l & 3) * 8;
    const ushort* Ahg = Ah + (size_t)(m0 + srowA) * 1024 + scol;
    const ushort* Bhg = Bh + (size_t)(n0 + srowB) * 1024 + scol;
    const ushort* Alg = SPLIT ? Al + (size_t)(m0 + srowA) * 1024 + scol : nullptr;
    const ushort* Blg = SPLIT ? Bl + (size_t)(n0 + srowB) * 1024 + scol : nullptr;

    floatx4 acc[4][JT] = {};
    const int fr = l & 15;
    const int fq = (l >> 4) * 16;

    for (int kb = 0; kb < 1024; kb += 32) {
        if (kb) __syncthreads();
        gload16(Ahg + kb,             a_h + w*2048);
        gload16(Ahg + kb + 16*1024,   a_h + w*2048 + 1024);
        if (BN == 128) {
            gload16(Bhg + kb,             b_h + w*2048);
            gload16(Bhg + kb + 16*1024,   b_h + w*2048 + 1024);
        } else {
            gload16(Bhg + kb,             b_h + w*1024);
        }
        if (SPLIT) {
            gload16(Alg + kb,           a_l + w*2048);
            gload16(Alg + kb + 16*1024, a_l + w*2048 + 1024);
            if (BN == 128) {
                gload16(Blg + kb,           b_l + w*2048);
                gload16(Blg + kb + 16*1024, b_l + w*2048 + 1024);
            } else {
                gload16(Blg + kb,           b_l + w*1024);
            }
        }
        __syncthreads();
        short8 fah[4], fbh[JT], fal[4], fbl[JT];
        #pragma unroll
        for (int t = 0; t < 4; ++t) {
            fah[t] = *(const short8*)(a_h + ((wm*64 + t*16 + fr) << 6) + fq);
            if (SPLIT)
                fal[t] = *(const short8*)(a_l + ((wm*64 + t*16 + fr) << 6) + fq);
        }
        #pragma unroll
        for (int t = 0; t < JT; ++t) {
            fbh[t] = *(const short8*)(b_h + ((wn*(BN/2) + t*16 + fr) << 6) + fq);
            if (SPLIT)
                fbl[t] = *(const short8*)(b_l + ((wn*(BN/2) + t*16 + fr) << 6) + fq);
        }
        #pragma unroll
        for (int it = 0; it < 4; ++it)
            #pragma unroll
            for (int jt = 0; jt < JT; ++jt) {
                acc[it][jt] = __builtin_amdgcn_mfma_f32_16x16x32_bf16(
                    fah[it], fbh[jt], acc[it][jt], 0, 0, 0);
                if (SPLIT) {
                    acc[it][jt] = __builtin_amdgcn_mfma_f32_16x16x32_bf16(
                        fah[it], fbl[jt], acc[it][jt], 0, 0, 0);
                    acc[it][jt] = __builtin_amdgcn_mfma_f32_16x16x32_bf16(
                        fal[it], fbh[jt], acc[it][jt], 0, 0, 0);
                }
            }
    }

    const int row0 = (l >> 4) * 4;   // C: row=(l>>4)*4+reg, col=l&15
    const int col  = l & 15;

    if (EPI == 0) {
        #pragma unroll
        for (int it = 0; it < 4; ++it)
            #pragma unroll
            for (int jt = 0; jt < JT; ++jt)
                #pragma unroll
                for (int r = 0; r < 4; ++r) {
                    int gm = m0 + wm*64 + it*16 + row0 + r;
                    int gn = n0 + wn*(BN/2) + jt*16 + col;
                    cout[(size_t)gm * ldc + gn] = acc[it][jt][r];
                }
    } else {
        // transposed v store: rows m = h*64+d, cols n = token
        #pragma unroll
        for (int it = 0; it < 4; ++it)
            #pragma unroll
            for (int jt = 0; jt < JT; ++jt)
                #pragma unroll
                for (int r = 0; r < 4; ++r) {
                    int md = m0 + wm*64 + it*16 + row0 + r;
                    int t  = n0 + wn*(BN/2) + jt*16 + col;
                    int bb = t >> 11, ss = t & (SEQ - 1);
                    qwb[((size_t)bb << 21) + (size_t)md * SEQ + ss] = f2bf(acc[it][jt][r]);
                }
    }
}

// ---------------------------------------------------------------------------
// qk GEMM (plain bf16, BN=128) with FUSED splat epilogue (never materializes
// q/k). Wave tile = 64 tokens x one full head. After the K-loop:
//  1) store wave's 64x64 tile bf16 to LDS, XOR-swizzled 16B blocks;
//  2) lane = token: iterate logical col-octets cb (physical block cb^(l&7)):
//     q via ds_read_b128; centers via WAVE-UNIFORM broadcast float4 reads;
//     dq[sp] += (q-c)^2 running accumulators;
//  3) w_sp = exp(-0.5*dq/s^2)*sigmoid(amp) with per-block precomputed Pr.
// ---------------------------------------------------------------------------
__device__ __forceinline__ void qk_splat_body(
    int bx, int by, char* smem,
    const ushort* __restrict__ Ah, const ushort* __restrict__ Bh,
    ushort* __restrict__ qwb, ushort* __restrict__ kwb,
    const float* __restrict__ centers, const float* __restrict__ lscales,
    const float* __restrict__ amps)
{
    const int tid = threadIdx.x;
    const int l = tid & 63;
    const int w = tid >> 6;
    const int wm = w >> 1, wn = w & 1;
    const int n0 = bx * 128;
    const int m0 = by * 128;
    char* a_h = smem;
    char* b_h = smem + 8192;
    float* Cst = (float*)(smem + 32768);   // [2 heads][16 sp][64] f32, 8KB
    float* Pr  = (float*)(smem + 40960);   // [2 heads][{coef,amp}][16]

    const int hb = (n0 & 1023) >> 6;       // first head of this block
    {
        const float* src = centers + (size_t)hb * 1024;
        float4 v0 = *(const float4*)(src + tid*8);
        float4 v1 = *(const float4*)(src + tid*8 + 4);
        *(float4*)(Cst + tid*8)     = v0;
        *(float4*)(Cst + tid*8 + 4) = v1;
    }
    if (tid < 32) {
        int hl = tid >> 4, sp = tid & 15;
        float s2 = __expf(2.f * lscales[(hb + hl)*16 + sp]);
        Pr[hl*32 + sp]      = -0.5f / s2;
        Pr[hl*32 + 16 + sp] = 1.f / (1.f + __expf(-amps[(hb + hl)*16 + sp]));
    }

    const int srow = 32 * w + (l >> 2);
    const int scol = (l & 3) * 8;
    const ushort* Ahg = Ah + (size_t)(m0 + srow) * 1024 + scol;
    const ushort* Bhg = Bh + (size_t)(n0 + srow) * 1024 + scol;

    floatx4 acc[4][4] = {};
    const int fr = l & 15;
    const int fq = (l >> 4) * 16;

    for (int kb = 0; kb < 1024; kb += 32) {
        if (kb) __syncthreads();
        gload16(Ahg + kb,             a_h + w*2048);
        gload16(Ahg + kb + 16*1024,   a_h + w*2048 + 1024);
        gload16(Bhg + kb,             b_h + w*2048);
        gload16(Bhg + kb + 16*1024,   b_h + w*2048 + 1024);
        __syncthreads();
        short8 fah[4], fbh[4];
        #pragma unroll
        for (int t = 0; t < 4; ++t) {
            fah[t] = *(const short8*)(a_h + ((wm*64 + t*16 + fr) << 6) + fq);
            fbh[t] = *(const short8*)(b_h + ((wn*64 + t*16 + fr) << 6) + fq);
        }
        #pragma unroll
        for (int it = 0; it < 4; ++it)
            #pragma unroll
            for (int jt = 0; jt < 4; ++jt)
                acc[it][jt] = __builtin_amdgcn_mfma_f32_16x16x32_bf16(
                    fah[it], fbh[jt], acc[it][jt], 0, 0, 0);
    }

    // ---- fused splat epilogue ----
    __syncthreads();                       // staging dead; Cst/Pr ready
    const int row0 = (l >> 4) * 4;
    const int col  = l & 15;
    ushort* qt = (ushort*)(smem + w*8192); // wave's 64x64 bf16 tile

    #pragma unroll
    for (int it = 0; it < 4; ++it)
        #pragma unroll
        for (int jt = 0; jt < 4; ++jt)
            #pragma unroll
            for (int r = 0; r < 4; ++r) {
                int tok = it*16 + row0 + r;
                int c   = jt*16 + col;
                qt[tok*64 + ((((c >> 3) ^ (tok & 7)) << 3) | (c & 7))] =
                    f2bf(acc[it][jt][r]);
            }

    const float* cw  = Cst + wn*1024;      // this wave's head's centers
    const float* prc = Pr  + wn*32;
    float dq[16];
    #pragma unroll
    for (int sp = 0; sp < 16; ++sp) dq[sp] = 0.f;

    #pragma unroll
    for (int cb = 0; cb < 8; ++cb) {       // logical col-octet
        short8 v = *(const short8*)(qt + l*64 + ((cb ^ (l & 7)) << 3));
        float qv8[8];
        #pragma unroll
        for (int i = 0; i < 8; ++i) qv8[i] = bf2f((ushort)v[i]);
        const float* cbp = cw + cb*8;      // wave-uniform broadcast reads
        #pragma unroll
        for (int sp = 0; sp < 16; ++sp) {
            float4 c0 = *(const float4*)(cbp + sp*64);
            float4 c1 = *(const float4*)(cbp + sp*64 + 4);
            float t0 = qv8[0] - c0.x; dq[sp] = fmaf(t0, t0, dq[sp]);
            float t1 = qv8[1] - c0.y; dq[sp] = fmaf(t1, t1, dq[sp]);
            float t2 = qv8[2] - c0.z; dq[sp] = fmaf(t2, t2, dq[sp]);
            float t3 = qv8[3] - c0.w; dq[sp] = fmaf(t3, t3, dq[sp]);
            float t4 = qv8[4] - c1.x; dq[sp] = fmaf(t4, t4, dq[sp]);
            float t5 = qv8[5] - c1.y; dq[sp] = fmaf(t5, t5, dq[sp]);
            float t6 = qv8[6] - c1.z; dq[sp] = fmaf(t6, t6, dq[sp]);
            float t7 = qv8[7] - c1.w; dq[sp] = fmaf(t7, t7, dq[sp]);
        }
    }

    const int hh = hb + wn;
    const int tg = m0 + wm*64 + l;
    const int bb = tg >> 11, ss = tg & (SEQ - 1);
    ushort* obuf = (n0 < 1024) ? qwb : kwb;
    ushort o16[16];
    #pragma unroll
    for (int sp = 0; sp < 16; ++sp)
        o16[sp] = f2bf(__expf(dq[sp] * prc[sp]) * prc[16 + sp]);
    ushort* op = obuf + (((size_t)(bb*NH + hh))*SEQ + ss)*16;
    *(short8*)(op)     = *(short8*)(o16);
    *(short8*)(op + 8) = *(short8*)(o16 + 8);
}

// Dispatch B: v^T GEMM (split, BN=64, 512 blocks) + traj[0,3072)
__global__ __launch_bounds__(256) void gemmV_traj_kernel(
    const ushort* __restrict__ Ah, const ushort* __restrict__ Al,
    const ushort* __restrict__ Bh, const ushort* __restrict__ Bl,
    ushort* __restrict__ vbt,
    const float* __restrict__ x, const float* __restrict__ sbuf,
    const float* __restrict__ invbuf, float* __restrict__ traj_out)
{
    __shared__ __align__(16) char smem[2 * (8192 + 64*64)];
    const int blk = blockIdx.x;
    if (blk < 512) {
        gemm_body<1,2,64>(blk & 63, blk >> 6, smem, Ah, Al, Bh, Bl,
                          nullptr, 0, vbt);
    } else {
        traj_body(blk - 512, x, sbuf, invbuf, traj_out);
    }
}

// Dispatch C: q/k GEMM + fused splat (512 blocks) + traj[3072,4096)
__global__ __launch_bounds__(256) void qksplat_traj_kernel(
    const ushort* __restrict__ Ah, const ushort* __restrict__ Bh,
    ushort* __restrict__ qwb, ushort* __restrict__ kwb,
    const float* __restrict__ centers, const float* __restrict__ lscales,
    const float* __restrict__ amps,
    const float* __restrict__ x, const float* __restrict__ sbuf,
    const float* __restrict__ invbuf, float* __restrict__ traj_out)
{
    __shared__ __align__(16) char smem[41216];
    const int blk = blockIdx.x;
    if (blk < 512) {
        qk_splat_body(blk & 15, blk >> 4, smem, Ah, Bh,
                      qwb, kwb, centers, lscales, amps);
    } else {
        traj_body(blk - 512 + 3072, x, sbuf, invbuf, traj_out);
    }
}

// Dispatch F: out GEMM (split, BN=64, fp32 out)
__global__ __launch_bounds__(256) void gemmO_kernel(
    const ushort* __restrict__ Ah, const ushort* __restrict__ Al,
    const ushort* __restrict__ Bh, const ushort* __restrict__ Bl,
    float* __restrict__ cout)
{
    __shared__ __align__(16) char smem[2 * (8192 + 64*64)];
    gemm_body<1,0,64>(blockIdx.x, blockIdx.y, smem, Ah, Al, Bh, Bl,
                      cout, 1024, nullptr);
}

// ---------------------------------------------------------------------------
// MFMA flash attention, v3: all-register P (no P LDS round-trip).
// 256 threads / 4 waves (qh, kh); QK quadrant via 1x mfma_32x32x16, exp,
// in-register redistribution to PV A-fragment via cvt_pk + permlane32_swap;
// PV via 4x mfma_32x32x16 from xor-swizzled double-buffered V tile.
// One barrier per 64-key tile; kh-partials combined through LDS at the end.
// ---------------------------------------------------------------------------
__global__ __launch_bounds__(256, 4) void attn_kernel(
    const ushort* __restrict__ qw, const ushort* __restrict__ kw,
    const ushort* __restrict__ vbt, ushort* __restrict__ hoh, ushort* __restrict__ hol)
{
    // [0,16K): V^T double buffer (2 x 8KB, [64 d][8 blk of 16B], blk^=(d&7))
    // [16K,16K+512): z combine buffer
    __shared__ __align__(16) char smem[16384 + 512];
    const int tid = threadIdx.x;
    const int l   = tid & 63;
    const int w   = tid >> 6;        // 0..3
    const int qh  = w >> 1;
    const int kh  = w & 1;
    const int l31 = l & 31;
    const int hi  = l >> 5;
    const int bh = blockIdx.y;
    const int b = bh >> 4;
    const int h = bh & 15;
    const int s0 = blockIdx.x * 64;

    // Q fragment (B operand): query s0+qh*32+l31, splat k = hi*8..+8
    short8 qf = *(const short8*)(qw + ((size_t)bh*SEQ + s0 + qh*32 + l31)*16 + hi*8);

    // K fragment source (A operand), direct from global (L2-hot)
    const ushort* kfp = kw + ((size_t)bh*SEQ + kh*32 + l31)*16 + hi*8;
    const ushort* vtb = vbt + ((size_t)(b*1024 + h*64))*SEQ;

    // V stage sources (pre-swizzled global addr -> linear LDS dest)
    const int dA = w*16 + (l >> 3);
    const int dB = dA + 8;
    const ushort* vsA = vtb + (size_t)dA*SEQ + ((l & 7) ^ (dA & 7))*8;
    const ushort* vsB = vtb + (size_t)dB*SEQ + ((l & 7) ^ (dB & 7))*8;

    floatx16 acc0 = {}, acc1 = {};
    floatx16 zero16 = {};
    float zpart = 0.f;

    // prologue: stage tile 0 into buf 0, load kf for tile 0
    gload16(vsA, smem + w*2048);
    gload16(vsB, smem + w*2048 + 1024);
    short8 kf = *(const short8*)kfp;

    for (int jt = 0; jt < 32; ++jt) {
        __syncthreads();   // drains own vmcnt/lgkm: stage(jt) landed, reads of buf^1 done
        char* bufn = smem + ((jt + 1) & 1)*8192;
        if (jt < 31) {
            gload16(vsA + (jt + 1)*64, bufn + w*2048);
            gload16(vsB + (jt + 1)*64, bufn + w*2048 + 1024);
        }
        // QK^T quadrant: C[key][query], key=(r&3)+8*(r>>2)+4*hi (+kh*32), q=l31 (+qh*32)
        floatx16 sc = __builtin_amdgcn_mfma_f32_32x32x16_bf16(kf, qf, zero16, 0, 0, 0);
        if (jt < 31) kf = *(const short8*)(kfp + (jt + 1)*1024);

        float e[16];
        #pragma unroll
        for (int r = 0; r < 16; ++r) e[r] = __expf(sc[r]);
        float zs = 0.f;
        #pragma unroll
        for (int r = 0; r < 16; ++r) zs += e[r];
        zpart += zs;

        // pack to PV A-fragments (lane q=l31, k=8*hi+0..7)
        unsigned p0 = cvtpk(e[0],  e[1]),  p1 = cvtpk(e[2],  e[3]);
        unsigned p2 = cvtpk(e[4],  e[5]),  p3 = cvtpk(e[6],  e[7]);
        unsigned p4 = cvtpk(e[8],  e[9]),  p5 = cvtpk(e[10], e[11]);
        unsigned p6 = cvtpk(e[12], e[13]), p7 = cvtpk(e[14], e[15]);
        plswap(p0, p2); plswap(p1, p3);   // kseg0: keys kh*32 + 0..15
        plswap(p4, p6); plswap(p5, p7);   // kseg1: keys kh*32 + 16..31
        union { unsigned u[4]; short8 s; } ua, ub;
        ua.u[0] = p0; ua.u[1] = p1; ua.u[2] = p2; ua.u[3] = p3;
        ub.u[0] = p4; ub.u[1] = p5; ub.u[2] = p6; ub.u[3] = p7;

        // PV: O[q][d], V as B operand (lane: d col = l31 (+32*dt), 8 tokens)
        const ushort* buf = (const ushort*)(smem + (jt & 1)*8192);
        #pragma unroll
        for (int dt = 0; dt < 2; ++dt) {
            int row = dt*32 + l31;
            const ushort* vr = buf + row*64;
            int bk0 = (kh*4 + hi)     ^ (row & 7);
            int bk1 = (kh*4 + 2 + hi) ^ (row & 7);
            short8 vb0 = *(const short8*)(vr + bk0*8);
            short8 vb1 = *(const short8*)(vr + bk1*8);
            if (dt == 0) {
                acc0 = __builtin_amdgcn_mfma_f32_32x32x16_bf16(ua.s, vb0, acc0, 0, 0, 0);
                acc0 = __builtin_amdgcn_mfma_f32_32x32x16_bf16(ub.s, vb1, acc0, 0, 0, 0);
            } else {
                acc1 = __builtin_amdgcn_mfma_f32_32x32x16_bf16(ua.s, vb0, acc1, 0, 0, 0);
                acc1 = __builtin_amdgcn_mfma_f32_32x32x16_bf16(ub.s, vb1, acc1, 0, 0, 0);
            }
        }
    }

    __syncthreads();   // drain everything before aliasing V buffers

    float* cb = (float*)smem;              // [qh*32+q][64 d] f32 = 16KB
    float* zb = (float*)(smem + 16384);    // [kh][64] f32 = 512B

    // z across hi halves: both halves end with total for their q
    unsigned za = __float_as_uint(zpart), zc = za;
    plswap(za, zc);
    float zq = __uint_as_float(za) + __uint_as_float(zc);
    if (l31 == l) zb[kh*64 + qh*32 + l31] = zq;   // lanes 0..31 only

    if (kh) {
        #pragma unroll
        for (int r = 0; r < 16; ++r) {
            int q = (r & 3) + 8*(r >> 2) + 4*hi;
            cb[(qh*32 + q)*64 + l31]      = acc0[r];
            cb[(qh*32 + q)*64 + 32 + l31] = acc1[r];
        }
    }
    __syncthreads();
    if (!kh) {
        #pragma unroll
        for (int r = 0; r < 16; ++r) {
            int q = (r & 3) + 8*(r >> 2) + 4*hi;
            float zt = zb[qh*32 + q] + zb[64 + qh*32 + q];
            float inv = 1.0f / zt;
            int s = s0 + qh*32 + q;
            size_t base = ((size_t)(b*SEQ + s))*1024 + h*64;
            float v0 = (acc0[r] + cb[(qh*32 + q)*64 + l31])      * inv;
            float v1 = (acc1[r] + cb[(qh*32 + q)*64 + 32 + l31]) * inv;
            ushort h0 = f2bf(v0);
            ushort h1 = f2bf(v1);
            hoh[base + l31]      = h0;
            hol[base + l31]      = f2bf(v0 - bf2f(h0));
            hoh[base + 32 + l31] = h1;
            hol[base + 32 + l31] = f2bf(v1 - bf2f(h1));
        }
    }
}

// ---------------------------------------------------------------------------
extern "C" void kernel_launch(void* const* d_in, const int* in_sizes, int n_in,
                              void* d_out, int out_size, void* d_ws, size_t ws_size,
                              hipStream_t stream)
{
    const float* x       = (const float*)d_in[0];
    const float* qkv_w   = (const float*)d_in[1];
    const float* out_w   = (const float*)d_in[2];
    const float* centers = (const float*)d_in[3];
    const float* lscales = (const float*)d_in[4];
    const float* amps    = (const float*)d_in[5];
    float* out  = (float*)d_out;                      // [B,S,D]
    float* traj = out + (size_t)NB*SEQ*DIM;           // [B,S,D]

    char* wsb = (char*)d_ws;                          // 40.03 MB total
    ushort* xh   = (ushort*)(wsb);                    // [0,8) MB  bf16 x hi
    ushort* xl   = (ushort*)(wsb + (8u<<20));         // [8,16) MB bf16 x lo
    ushort* wh   = (ushort*)(wsb + (16u<<20));        // [16,22) MB qkv_w hi (3072x1024)
    ushort* wlv  = (ushort*)(wsb + (22u<<20));        // [22,24) MB v-weight lo
    ushort* vbt  = (ushort*)(wsb + (24u<<20));        // [24,32) MB v^T bf16 [B,1024,S]
    ushort* owh  = (ushort*)(wsb + (32u<<20));        // [32,34) MB out_w hi
    ushort* owl  = (ushort*)(wsb + (34u<<20));        // [34,36) MB out_w lo
    ushort* qwbh = (ushort*)(wsb + (36u<<20));        // [36,38) MB q splat weights
    ushort* kwbh = (ushort*)(wsb + (38u<<20));        // [38,40) MB k splat weights
    float*  sbuf = (float*)(wsb + (40u<<20));         // 16 KB
    float*  invb = sbuf + 4096;                       // 16 KB
    // aliases (dead by the time they're written):
    ushort* hoh  = xh;                                // attn out hi (xh dead after C)
    ushort* hol  = xl;                                // attn out lo (xl dead after B)

    // A: input conversions + traj stats + out_w split
    front_kernel<<<9216, 256, 0, stream>>>(
        x, qkv_w, out_w, xh, xl, wh, wlv, owh, owl, sbuf, invb);
    // B: v^T GEMM (split) + traj[0,3072)
    gemmV_traj_kernel<<<3584, 256, 0, stream>>>(
        wh + 2048*1024, wlv, xh, xl, vbt, x, sbuf, invb, traj);
    // C: qk GEMM + fused splat + traj[3072,4096)
    qksplat_traj_kernel<<<1536, 256, 0, stream>>>(
        xh, wh, qwbh, kwbh, centers, lscales, amps, x, sbuf, invb, traj);
    // attention
    attn_kernel<<<dim3(32, 32), 256, 0, stream>>>(qwbh, kwbh, vbt, hoh, hol);
    // out = ho @ out_w^T (split, fp32 out)
    gemmO_kernel<<<dim3(16, 32), 256, 0, stream>>>(hoh, hol, owh, owl, out);
}